// Round 3
// baseline (508.272 us; speedup 1.0000x reference)
//
#include <hip/hip_runtime.h>
#include <math.h>

#define NPGN 61
#define NGRAPH 128
#define NNODES (NPGN*NGRAPH)   // 7808
#define EPG 3660               // 61*60 edges per graph

typedef float float4v __attribute__((ext_vector_type(4)));
typedef short bf16x8 __attribute__((ext_vector_type(8)));
typedef unsigned short u16;

__device__ __forceinline__ u16 f2bf(float v){
  union { float f; unsigned u; } x; x.f = v;
  unsigned r = (x.u + 0x7FFFu + ((x.u >> 16) & 1u)) >> 16;
  return (u16)r;
}
__device__ __forceinline__ float bf2f(unsigned u){
  union { unsigned u; float f; } x; x.u = u << 16;
  return x.f;
}

// ---------------- prep: weight re-layouts ----------------
// w1b[f*320 + kk*64 + c] bf16 ; w2t[(c*3+t)*64+f] fp32 ; w0t[k*64+f] fp32 ;
// gwt_l[j*Cin + k] = gw_l[k*128 + j] bf16 (K-minor for MFMA frags)
__global__ __launch_bounds__(256) void k_prep_w(const float* __restrict__ w0,
    const float* __restrict__ w1, const float* __restrict__ w2,
    const float* __restrict__ gw0, const float* __restrict__ gw1, const float* __restrict__ gw2,
    float* __restrict__ w0t, u16* __restrict__ w1b, float* __restrict__ w2t,
    u16* __restrict__ gwt0, u16* __restrict__ gwt1, u16* __restrict__ gwt2){
  int idx = blockIdx.x*256 + threadIdx.x;
  if (idx < 20480){
    int f = idx / 320, r = idx - f*320;
    int kk = r >> 6, c = r & 63;
    w1b[idx] = f2bf(w1[f*320 + c*5 + kk]);
  } else if (idx < 32768){
    int j = idx - 20480; int ck = j >> 6, f = j & 63; w2t[j] = w2[f*192 + ck];
  } else if (idx < 40960){
    int j = idx - 32768; int jj = j >> 6, k = j & 63; gwt0[j] = f2bf(gw0[k*128 + jj]);
  } else if (idx < 57344){
    int j = idx - 40960; int jj = j >> 7, k = j & 127; gwt1[j] = f2bf(gw1[k*128 + jj]);
  } else if (idx < 73728){
    int j = idx - 57344; int jj = j >> 7, k = j & 127; gwt2[j] = f2bf(gw2[k*128 + jj]);
  } else if (idx < 74176){
    int j = idx - 73728; int k = j >> 6, f = j & 63; w0t[j] = w0[f*7 + k];
  }
}

// ---------------- edge weights: ew = tanh(ef @ w + b), plus transposed output
__global__ __launch_bounds__(256) void k_edge(const float* __restrict__ ef,
    const float* __restrict__ eww, const float* __restrict__ ewb,
    float* __restrict__ ew, float* __restrict__ out2){
  __shared__ float t[32][129];
  int i0 = blockIdx.x * 32;
  int tid = threadIdx.x;
  float w0 = eww[0], w1 = eww[1], w2 = eww[2], b = ewb[0];
  #pragma unroll 1
  for (int it = 0; it < 16; it++){
    int idx = it*256 + tid;
    int g = idx >> 5, ii = idx & 31;
    int i = i0 + ii;
    if (i < EPG){
      size_t e = (size_t)g*EPG + i;
      const float* p = ef + e*3;
      float v = tanhf(p[0]*w0 + p[1]*w1 + p[2]*w2 + b);
      ew[e] = v;
      t[ii][g] = v;
    }
  }
  __syncthreads();
  #pragma unroll 1
  for (int it = 0; it < 16; it++){
    int idx = it*256 + tid;
    int ii = idx >> 7, g = idx & 127;
    int i = i0 + ii;
    if (i < EPG) out2[(size_t)i*128 + g] = t[ii][g];
  }
}

// ---------------- dense per-graph edge matrix, bf16, [g][64][72] (zero-pad)
#define EW_STR 72
__global__ __launch_bounds__(256) void k_ewmat(const float* __restrict__ ew, u16* __restrict__ ewg_bf){
  int g = blockIdx.x, tid = threadIdx.x;
  __shared__ u16 t[64*EW_STR];
  unsigned* td = (unsigned*)t;
  for (int idx = tid; idx < 64*EW_STR/2; idx += 256) td[idx] = 0;
  __syncthreads();
  const float* e = ew + (size_t)g*EPG;
  for (int idx = tid; idx < EPG; idx += 256){
    int s = idx/60, r = idx - s*60;
    int d = r + (r >= s ? 1 : 0);
    t[d*EW_STR + s] = f2bf(e[idx]);
  }
  __syncthreads();
  unsigned* dst = (unsigned*)ewg_bf + (size_t)g*(64*EW_STR/2);
  for (int idx = tid; idx < 64*EW_STR/2; idx += 256) dst[idx] = td[idx];
}

// ---------------- conv stack: 4 independent waves/block, 1 node/wave, no barriers
#define A0T_STR 72   // u16 units (144 B)
#define C1_STR 40    // u16 units (80 B)
__global__ __launch_bounds__(256) void k_conv(const float* __restrict__ x,
    const float* __restrict__ w0t, const float* __restrict__ b0,
    const u16* __restrict__ w1b, const float* __restrict__ b1,
    const float* __restrict__ w2t, const float* __restrict__ b2,
    float* __restrict__ h0){
  int w = threadIdx.x >> 6, lane = threadIdx.x & 63;
  int n = blockIdx.x*4 + w;
  __shared__ __align__(16) u16 a0t_s[4][36*A0T_STR];  // 5184 B/wave, c1 overlays
  __shared__ float xs[4][160];
  __shared__ __align__(8) u16 a1s[4][64*4];
  u16* a0t = a0t_s[w];

  for (int i = lane; i < 160; i += 64) xs[w][i] = x[(size_t)n*160 + i];
  float w0r[7];
  #pragma unroll
  for (int k = 0; k < 7; k++) w0r[k] = w0t[k*64 + lane];
  float b0f = b0[lane];
  #pragma unroll
  for (int rp = 0; rp < 36; rp++)
    if (rp < 2 || rp >= 24) a0t[rp*A0T_STR + lane] = 0;

  // conv0 (K=7) + relu + maxpool7 : 160 -> 154 -> 22 ; lane = channel
  #pragma unroll 1
  for (int q = 0; q < 22; q++){
    float win[13];
    #pragma unroll
    for (int j = 0; j < 13; j++) win[j] = xs[w][q*7 + j];
    float m = 0.f;
    #pragma unroll
    for (int r = 0; r < 7; r++){
      float s = b0f;
      #pragma unroll
      for (int k = 0; k < 7; k++) s += w0r[k]*win[r+k];
      m = fmaxf(m, s);
    }
    a0t[(2+q)*A0T_STR + lane] = f2bf(m);
  }

  // conv1 MFMA: C[64f][22p] = W[64f][320] * B[320][22p], k = kk*64 + c
  int q = lane >> 4, r16 = lane & 15;
  float4v acc[4][2];
  #pragma unroll
  for (int mt = 0; mt < 4; mt++)
    #pragma unroll
    for (int nt = 0; nt < 2; nt++)
      acc[mt][nt] = (float4v){0.f,0.f,0.f,0.f};
  #pragma unroll 1
  for (int ks = 0; ks < 10; ks++){
    int kk = ks >> 1;
    int cbase = (ks & 1)*32 + q*8;
    bf16x8 af[4];
    #pragma unroll
    for (int mt = 0; mt < 4; mt++)
      af[mt] = *(const bf16x8*)(w1b + (16*mt + r16)*320 + ks*32 + q*8);
    bf16x8 bv[2];
    #pragma unroll
    for (int nt = 0; nt < 2; nt++)
      bv[nt] = *(const bf16x8*)(a0t + (r16 + 16*nt + kk)*A0T_STR + cbase);
    #pragma unroll
    for (int mt = 0; mt < 4; mt++)
      #pragma unroll
      for (int nt = 0; nt < 2; nt++)
        acc[mt][nt] = __builtin_amdgcn_mfma_f32_16x16x32_bf16(af[mt], bv[nt], acc[mt][nt], 0, 0, 0);
  }

  // bias + relu -> c1 (bf16, overlays a0t; same-wave DS ops are in-order)
  u16* c1 = a0t;
  #pragma unroll
  for (int mt = 0; mt < 4; mt++){
    float4 bb = *(const float4*)(b1 + 16*mt + 4*q);
    #pragma unroll
    for (int reg = 0; reg < 4; reg++){
      int m = 16*mt + q*4 + reg;
      float bv_ = ((const float*)&bb)[reg];
      c1[m*C1_STR + r16] = f2bf(fmaxf(acc[mt][0][reg] + bv_, 0.f));
      if (r16 <= 4)
        c1[m*C1_STR + 16 + r16] = f2bf(fmaxf(acc[mt][1][reg] + bv_, 0.f));
    }
  }

  // maxpool7 (21 -> 3), lane = channel
  {
    bf16x8 f0 = *(const bf16x8*)(c1 + lane*C1_STR);
    bf16x8 f1 = *(const bf16x8*)(c1 + lane*C1_STR + 8);
    bf16x8 f2 = *(const bf16x8*)(c1 + lane*C1_STR + 16);
    float v[24];
    #pragma unroll
    for (int j = 0; j < 8; j++){
      v[j]    = bf2f((u16)f0[j]);
      v[8+j]  = bf2f((u16)f1[j]);
      v[16+j] = bf2f((u16)f2[j]);
    }
    unsigned pk[2]; float mx[3];
    #pragma unroll
    for (int t = 0; t < 3; t++){
      float m = v[t*7];
      #pragma unroll
      for (int r = 1; r < 7; r++) m = fmaxf(m, v[t*7+r]);
      mx[t] = m;
    }
    pk[0] = (unsigned)f2bf(mx[0]) | ((unsigned)f2bf(mx[1]) << 16);
    pk[1] = (unsigned)f2bf(mx[2]);
    unsigned* a1d = (unsigned*)a1s[w];
    a1d[lane*2] = pk[0]; a1d[lane*2+1] = pk[1];
  }

  // conv2 (K=3): 3 -> 1
  float s2 = b2[lane];
  const unsigned* a1d = (const unsigned*)a1s[w];
  #pragma unroll 1
  for (int c = 0; c < 64; c++){
    unsigned p0 = a1d[c*2], p1 = a1d[c*2+1];
    float t0 = bf2f(p0 & 0xffffu), t1 = bf2f(p0 >> 16), t2 = bf2f(p1 & 0xffffu);
    s2 += w2t[c*192 + lane]*t0 + w2t[c*192 + 64 + lane]*t1 + w2t[c*192 + 128 + lane]*t2;
  }
  h0[(size_t)n*64 + lane] = s2;
}

// ---------------- bn stats partials: coalesced row-major, 32 blocks ---------
__global__ __launch_bounds__(256) void k_stats1(const float* __restrict__ h0, float* __restrict__ stat1p){
  int b = blockIdx.x, tid = threadIdx.x;
  int col = tid & 63, rg = tid >> 6;
  float s = 0.f, s2 = 0.f;
  int r0 = b*244 + rg*61;
  #pragma unroll 1
  for (int t = 0; t < 61; t++){
    float v = h0[(size_t)(r0 + t)*64 + col];
    s += v; s2 += v*v;
  }
  __shared__ float ls[256], ls2[256];
  ls[tid] = s; ls2[tid] = s2;
  __syncthreads();
  if (tid < 64){
    stat1p[b*128 + tid]      = ls[tid] + ls[tid+64] + ls[tid+128] + ls[tid+192];
    stat1p[b*128 + 64 + tid] = ls2[tid] + ls2[tid+64] + ls2[tid+128] + ls2[tid+192];
  }
}

__global__ __launch_bounds__(256) void k_stats2(const u16* __restrict__ hB, float* __restrict__ stat2p){
  int b = blockIdx.x, tid = threadIdx.x;
  int col = tid & 127, rg = tid >> 7;
  float s = 0.f, s2 = 0.f;
  int r0 = b*244 + rg*122;
  #pragma unroll 1
  for (int t = 0; t < 122; t++){
    float v = bf2f(hB[(size_t)(r0 + t)*128 + col]);
    s += v; s2 += v*v;
  }
  __shared__ float ls[512];
  ls[tid] = s; ls[256 + tid] = s2;
  __syncthreads();
  if (tid < 128){
    stat2p[b*256 + tid]       = ls[tid] + ls[tid+128];
    stat2p[b*256 + 128 + tid] = ls[256+tid] + ls[256+tid+128];
  }
}

// ---------------- fused 3-layer GNN via MFMA, one block per graph -----------
#define HS_STR 136   // u16 (272 B)
#define HWT_STR 72   // u16 (144 B)
__global__ __launch_bounds__(256) void k_gnn(const float* __restrict__ h0,
    const float* __restrict__ stat1p,
    const float* __restrict__ bn1g, const float* __restrict__ bn1b,
    const u16* __restrict__ gwt0, const float* __restrict__ gb0,
    const u16* __restrict__ gwt1, const float* __restrict__ gb1,
    const u16* __restrict__ gwt2, const float* __restrict__ gb2,
    const u16* __restrict__ ewg_bf, u16* __restrict__ hB){
  int g = blockIdx.x, tid = threadIdx.x;
  int w = tid >> 6, lane = tid & 63, q = lane >> 4, r16 = lane & 15;
  __shared__ u16 hs[64*HS_STR];     // 17408 B  [node i][k]
  __shared__ u16 hwT[128*HWT_STR];  // 18432 B  [j][node s]
  __shared__ u16 ewl[64*EW_STR];    //  9216 B  [d][s]
  __shared__ float bsc[64], bsh[64];
  if (tid < 64){
    float s = 0.f, s2 = 0.f;
    #pragma unroll 1
    for (int r = 0; r < 32; r++){ s += stat1p[r*128 + tid]; s2 += stat1p[r*128 + 64 + tid]; }
    float m = s*(1.f/NNODES), v = s2*(1.f/NNODES) - m*m;
    float sc = rsqrtf(v + 1e-5f)*bn1g[tid];
    bsc[tid] = sc; bsh[tid] = bn1b[tid] - m*sc;
  }
  {
    const unsigned* src = (const unsigned*)ewg_bf + (size_t)g*(64*EW_STR/2);
    unsigned* dst = (unsigned*)ewl;
    for (int idx = tid; idx < 64*EW_STR/2; idx += 256) dst[idx] = src[idx];
  }
  {
    unsigned* hsd = (unsigned*)hs;
    for (int idx = tid; idx < 3*(HS_STR/2); idx += 256){
      int rr = 61 + idx/(HS_STR/2), cc = idx%(HS_STR/2);
      hsd[rr*(HS_STR/2) + cc] = 0;
    }
  }
  __syncthreads();
  {
    unsigned* hsd = (unsigned*)hs;
    for (int idx = tid; idx < 61*32; idx += 256){
      int i = idx >> 5, kw = idx & 31;
      float2 hv = *(const float2*)(h0 + ((size_t)g*61 + i)*64 + kw*2);
      int k0 = kw*2;
      float a = hv.x*bsc[k0] + bsh[k0];
      float b = hv.y*bsc[k0+1] + bsh[k0+1];
      hsd[i*(HS_STR/2) + kw] = (unsigned)f2bf(a) | ((unsigned)f2bf(b) << 16);
    }
  }
  __syncthreads();

  const u16* Wl[3] = {gwt0, gwt1, gwt2};
  const float* Bl[3] = {gb0, gb1, gb2};
  #pragma unroll 1
  for (int l = 0; l < 3; l++){
    const u16* W = Wl[l];
    const float* bias = Bl[l];
    int Cin = l ? 128 : 64;
    int ksn = Cin >> 5;
    // phase1: hwT[j][i] = bias[j] + sum_k Wt[j][k]*hs[i][k]
    #pragma unroll 1
    for (int mi = 0; mi < 2; mi++){
      int mt = w*2 + mi;
      bf16x8 af[4];
      #pragma unroll 1
      for (int ks = 0; ks < ksn; ks++)
        af[ks] = *(const bf16x8*)(W + (16*mt + r16)*Cin + ks*32 + q*8);
      float4 b4 = *(const float4*)(bias + 16*mt + 4*q);
      #pragma unroll 1
      for (int nt = 0; nt < 4; nt++){
        float4v acc = {b4.x, b4.y, b4.z, b4.w};
        #pragma unroll 1
        for (int ks = 0; ks < ksn; ks++){
          bf16x8 bv = *(const bf16x8*)(hs + (nt*16 + r16)*HS_STR + ks*32 + q*8);
          acc = __builtin_amdgcn_mfma_f32_16x16x32_bf16(af[ks], bv, acc, 0, 0, 0);
        }
        #pragma unroll
        for (int r = 0; r < 4; r++)
          hwT[(16*mt + 4*q + r)*HWT_STR + nt*16 + r16] = f2bf(acc[r]);
      }
    }
    __syncthreads();
    // phase2: hn[d][j] = sum_s Ew[d][s]*hwT[j][s]
    {
      bf16x8 af2[2];
      #pragma unroll
      for (int ks = 0; ks < 2; ks++)
        af2[ks] = *(const bf16x8*)(ewl + (16*w + r16)*EW_STR + ks*32 + q*8);
      #pragma unroll 1
      for (int nt = 0; nt < 8; nt++){
        float4v acc = {0.f,0.f,0.f,0.f};
        #pragma unroll
        for (int ks = 0; ks < 2; ks++){
          bf16x8 bv = *(const bf16x8*)(hwT + (nt*16 + r16)*HWT_STR + ks*32 + q*8);
          acc = __builtin_amdgcn_mfma_f32_16x16x32_bf16(af2[ks], bv, acc, 0, 0, 0);
        }
        if (l < 2){
          #pragma unroll
          for (int r = 0; r < 4; r++){
            int d = 16*w + 4*q + r;
            hs[d*HS_STR + nt*16 + r16] = f2bf(fmaxf(acc[r], 0.f));
          }
        } else {
          #pragma unroll
          for (int r = 0; r < 4; r++){
            int d = 16*w + 4*q + r;
            if (d < 61)
              hB[((size_t)g*61 + d)*128 + nt*16 + r16] = f2bf(acc[r]);
          }
        }
      }
    }
    __syncthreads();
  }
}

// ---------------- lin0 split-K via MFMA: block = (node pos i, o-half) -------
#define AS_STR 136
#define WT_STR 136
__global__ __launch_bounds__(256) void k_mlp0(const u16* __restrict__ hB,
    const float* __restrict__ stat2p,
    const float* __restrict__ bn2g, const float* __restrict__ bn2b,
    const float* __restrict__ lw0, float* __restrict__ part){
  int bi = blockIdx.x; int i = bi >> 1, oh = bi & 1;
  int tid = threadIdx.x, w = tid >> 6, lane = tid & 63, q = lane >> 4, r16 = lane & 15;
  __shared__ u16 As[128*AS_STR];   // 34816 B [g][k]
  __shared__ u16 wt[64*WT_STR];    // 17408 B [o_local][k]
  __shared__ float sc2[128], sh2[128];
  if (tid < 128){
    float s = 0.f, s2 = 0.f;
    #pragma unroll 1
    for (int r = 0; r < 32; r++){ s += stat2p[r*256 + tid]; s2 += stat2p[r*256 + 128 + tid]; }
    float m = s*(1.f/NNODES), v = s2*(1.f/NNODES) - m*m;
    float sc = rsqrtf(v + 1e-5f)*bn2g[tid];
    sc2[tid] = sc; sh2[tid] = bn2b[tid] - m*sc;
  }
  __syncthreads();
  {
    const unsigned* hbd = (const unsigned*)hB;
    unsigned* asd = (unsigned*)As;
    for (int idx = tid; idx < 8192; idx += 256){
      int gg = idx >> 6, kw = idx & 63;
      unsigned pv = hbd[((size_t)gg*61 + i)*64 + kw];
      int k0 = kw*2;
      float a = bf2f(pv & 0xffffu)*sc2[k0] + sh2[k0];
      float b = bf2f(pv >> 16)*sc2[k0+1] + sh2[k0+1];
      asd[gg*(AS_STR/2) + kw] = (unsigned)f2bf(a) | ((unsigned)f2bf(b) << 16);
    }
    for (int idx = tid; idx < 8192; idx += 256){
      int k = idx >> 6, o = idx & 63;
      wt[o*WT_STR + k] = f2bf(lw0[((size_t)i*128 + k)*128 + oh*64 + o]);
    }
  }
  __syncthreads();
  #pragma unroll 1
  for (int mi = 0; mi < 2; mi++){
    int mt = 2*w + mi;
    bf16x8 af[4];
    #pragma unroll
    for (int ks = 0; ks < 4; ks++)
      af[ks] = *(const bf16x8*)(As + (16*mt + r16)*AS_STR + ks*32 + q*8);
    #pragma unroll 1
    for (int nt = 0; nt < 4; nt++){
      float4v acc = {0.f,0.f,0.f,0.f};
      #pragma unroll
      for (int ks = 0; ks < 4; ks++){
        bf16x8 bv = *(const bf16x8*)(wt + (nt*16 + r16)*WT_STR + ks*32 + q*8);
        acc = __builtin_amdgcn_mfma_f32_16x16x32_bf16(af[ks], bv, acc, 0, 0, 0);
      }
      #pragma unroll
      for (int r = 0; r < 4; r++)
        part[(size_t)i*16384 + (size_t)(16*mt + 4*q + r)*128 + oh*64 + nt*16 + r16] = acc[r];
    }
  }
}

// ---------------- reduce partials + lin1 + lin2 + log_softmax ---------------
__global__ __launch_bounds__(256) void k_mlp1(const float* __restrict__ part,
    const float* __restrict__ lb0, const float* __restrict__ W1,
    const float* __restrict__ lb1, const float* __restrict__ W2,
    const float* __restrict__ lb2, float* __restrict__ out){
  int g = blockIdx.x, tid = threadIdx.x;
  int o = tid & 127, h = tid >> 7;
  __shared__ float y0[128], y1[128], red[256], y2[4];
  float acc = 0.f;
  int i0 = h*31, cnt = 31 - h;
  #pragma unroll 1
  for (int t = 0; t < cnt; t++)
    acc += part[(size_t)(i0 + t)*16384 + g*128 + o];
  red[tid] = acc;
  __syncthreads();
  if (tid < 128) y0[o] = fmaxf(red[o] + red[128 + o] + lb0[o], 0.f);
  __syncthreads();
  float a = 0.f;
  #pragma unroll 1
  for (int k = 0; k < 64; k++){
    int kk = h*64 + k;
    a += y0[kk]*W1[kk*128 + o];
  }
  red[tid] = a;
  __syncthreads();
  if (tid < 128) y1[o] = fmaxf(red[o] + red[128 + o] + lb1[o], 0.f);
  __syncthreads();
  if (tid < 4){
    float y = lb2[tid];
    #pragma unroll 1
    for (int k = 0; k < 128; k++) y += y1[k]*W2[k*4 + tid];
    y2[tid] = y;
  }
  __syncthreads();
  if (tid == 0){
    float m = fmaxf(fmaxf(y2[0],y2[1]), fmaxf(y2[2],y2[3]));
    float lse = m + logf(expf(y2[0]-m)+expf(y2[1]-m)+expf(y2[2]-m)+expf(y2[3]-m));
    out[g*4+0]=y2[0]-lse; out[g*4+1]=y2[1]-lse; out[g*4+2]=y2[2]-lse; out[g*4+3]=y2[3]-lse;
  }
}

extern "C" void kernel_launch(void* const* d_in, const int* in_sizes, int n_in,
                              void* d_out, int out_size, void* d_ws, size_t ws_size,
                              hipStream_t stream){
  const float* x    = (const float*)d_in[0];
  const float* ef   = (const float*)d_in[3];
  const float* cw0  = (const float*)d_in[4];
  const float* cb0  = (const float*)d_in[5];
  const float* cw1  = (const float*)d_in[6];
  const float* cb1  = (const float*)d_in[7];
  const float* cw2  = (const float*)d_in[8];
  const float* cb2  = (const float*)d_in[9];
  const float* bn1g = (const float*)d_in[10];
  const float* bn1b = (const float*)d_in[11];
  const float* gw0  = (const float*)d_in[12];
  const float* gb0  = (const float*)d_in[13];
  const float* gw1  = (const float*)d_in[14];
  const float* gb1  = (const float*)d_in[15];
  const float* gw2  = (const float*)d_in[16];
  const float* gb2  = (const float*)d_in[17];
  const float* bn2g = (const float*)d_in[18];
  const float* bn2b = (const float*)d_in[19];
  const float* lw0  = (const float*)d_in[20];
  const float* lb0  = (const float*)d_in[21];
  const float* lw1  = (const float*)d_in[22];
  const float* lb1  = (const float*)d_in[23];
  const float* lw2  = (const float*)d_in[24];
  const float* lb2  = (const float*)d_in[25];
  const float* eww  = (const float*)d_in[26];
  const float* ewb  = (const float*)d_in[27];
  float* out = (float*)d_out;

  float* ws   = (float*)d_ws;
  float* w1s  = ws;               // 10240 f (20480 u16)
  float* w2t  = w1s + 10240;      // 12288 f
  float* w0t  = w2t + 12288;      // 448 f
  float* gws0 = w0t + 448;        // 4096 f (8192 u16)
  float* gws1 = gws0 + 4096;      // 8192 f (16384 u16)
  float* gws2 = gws1 + 8192;      // 8192 f
  float* ew   = gws2 + 8192;      // 468480 f
  float* ewgs = ew + 468480;      // 294912 f (128*64*72 u16)
  float* h0   = ewgs + 294912;    // 499712 f
  float* hBs  = h0 + 499712;      // 499712 f (7808*128 u16)
  float* s1p  = hBs + 499712;     // 4096 f
  float* s2p  = s1p + 4096;       // 8192 f
  float* part = s2p + 8192;       // 999424 f    total ~ 11.3 MB

  u16* w1b    = (u16*)w1s;
  u16* gwt0   = (u16*)gws0;
  u16* gwt1   = (u16*)gws1;
  u16* gwt2   = (u16*)gws2;
  u16* ewg_bf = (u16*)ewgs;
  u16* hB     = (u16*)hBs;

  k_prep_w<<<290, 256, 0, stream>>>(cw0, cw1, cw2, gw0, gw1, gw2,
                                    w0t, w1b, w2t, gwt0, gwt1, gwt2);
  k_edge  <<<115, 256, 0, stream>>>(ef, eww, ewb, ew, out + 512);
  k_ewmat <<<NGRAPH, 256, 0, stream>>>(ew, ewg_bf);
  k_conv  <<<NNODES/4, 256, 0, stream>>>(x, w0t, cb0, w1b, cb1, w2t, cb2, h0);
  k_stats1<<<32, 256, 0, stream>>>(h0, s1p);
  k_gnn   <<<NGRAPH, 256, 0, stream>>>(h0, s1p, bn1g, bn1b,
                                       gwt0, gb0, gwt1, gb1, gwt2, gb2, ewg_bf, hB);
  k_stats2<<<32, 256, 0, stream>>>(hB, s2p);
  k_mlp0  <<<NPGN*2, 256, 0, stream>>>(hB, s2p, bn2g, bn2b, lw0, part);
  k_mlp1  <<<NGRAPH, 256, 0, stream>>>(part, lb0, lw1, lb1, lw2, lb2, out);
}

// Round 4
// 321.400 us; speedup vs baseline: 1.5814x; 1.5814x over previous
//
#include <hip/hip_runtime.h>
#include <math.h>

#define NPGN 61
#define NGRAPH 128
#define NNODES (NPGN*NGRAPH)   // 7808
#define EPG 3660               // 61*60 edges per graph

typedef float float4v __attribute__((ext_vector_type(4)));
typedef short bf16x8 __attribute__((ext_vector_type(8)));
typedef unsigned short u16;

__device__ __forceinline__ u16 f2bf(float v){
  union { float f; unsigned u; } x; x.f = v;
  unsigned r = (x.u + 0x7FFFu + ((x.u >> 16) & 1u)) >> 16;
  return (u16)r;
}
__device__ __forceinline__ float bf2f(unsigned u){
  union { unsigned u; float f; } x; x.u = u << 16;
  return x.f;
}

// ---------------- prep: weight re-layouts ----------------
__global__ __launch_bounds__(256) void k_prep_w(const float* __restrict__ w0,
    const float* __restrict__ w1, const float* __restrict__ w2,
    const float* __restrict__ gw0, const float* __restrict__ gw1, const float* __restrict__ gw2,
    float* __restrict__ w0t, u16* __restrict__ w1b, float* __restrict__ w2t,
    u16* __restrict__ gwt0, u16* __restrict__ gwt1, u16* __restrict__ gwt2){
  int idx = blockIdx.x*256 + threadIdx.x;
  if (idx < 20480){
    int f = idx / 320, r = idx - f*320;
    int kk = r >> 6, c = r & 63;
    w1b[idx] = f2bf(w1[f*320 + c*5 + kk]);
  } else if (idx < 32768){
    int j = idx - 20480; int ck = j >> 6, f = j & 63; w2t[j] = w2[f*192 + ck];
  } else if (idx < 40960){
    int j = idx - 32768; int jj = j >> 6, k = j & 63; gwt0[j] = f2bf(gw0[k*128 + jj]);
  } else if (idx < 57344){
    int j = idx - 40960; int jj = j >> 7, k = j & 127; gwt1[j] = f2bf(gw1[k*128 + jj]);
  } else if (idx < 73728){
    int j = idx - 57344; int jj = j >> 7, k = j & 127; gwt2[j] = f2bf(gw2[k*128 + jj]);
  } else if (idx < 74176){
    int j = idx - 73728; int k = j >> 6, f = j & 63; w0t[j] = w0[f*7 + k];
  }
}

// ---------------- edge weights: ew = tanh(ef @ w + b), plus transposed output
__global__ __launch_bounds__(256) void k_edge(const float* __restrict__ ef,
    const float* __restrict__ eww, const float* __restrict__ ewb,
    float* __restrict__ ew, float* __restrict__ out2){
  __shared__ float t[32][129];
  int i0 = blockIdx.x * 32;
  int tid = threadIdx.x;
  float w0 = eww[0], w1 = eww[1], w2 = eww[2], b = ewb[0];
  #pragma unroll 1
  for (int it = 0; it < 16; it++){
    int idx = it*256 + tid;
    int g = idx >> 5, ii = idx & 31;
    int i = i0 + ii;
    if (i < EPG){
      size_t e = (size_t)g*EPG + i;
      const float* p = ef + e*3;
      float v = tanhf(p[0]*w0 + p[1]*w1 + p[2]*w2 + b);
      ew[e] = v;
      t[ii][g] = v;
    }
  }
  __syncthreads();
  #pragma unroll 1
  for (int it = 0; it < 16; it++){
    int idx = it*256 + tid;
    int ii = idx >> 7, g = idx & 127;
    int i = i0 + ii;
    if (i < EPG) out2[(size_t)i*128 + g] = t[ii][g];
  }
}

// ---------------- dense per-graph edge matrix, bf16, [g][64][72] (zero-pad)
#define EW_STR 72
__global__ __launch_bounds__(256) void k_ewmat(const float* __restrict__ ew, u16* __restrict__ ewg_bf){
  int g = blockIdx.x, tid = threadIdx.x;
  __shared__ u16 t[64*EW_STR];
  unsigned* td = (unsigned*)t;
  for (int idx = tid; idx < 64*EW_STR/2; idx += 256) td[idx] = 0;
  __syncthreads();
  const float* e = ew + (size_t)g*EPG;
  for (int idx = tid; idx < EPG; idx += 256){
    int s = idx/60, r = idx - s*60;
    int d = r + (r >= s ? 1 : 0);
    t[d*EW_STR + s] = f2bf(e[idx]);
  }
  __syncthreads();
  unsigned* dst = (unsigned*)ewg_bf + (size_t)g*(64*EW_STR/2);
  for (int idx = tid; idx < 64*EW_STR/2; idx += 256) dst[idx] = td[idx];
}

// ---------------- conv stack: 4 independent waves/block, 1 node/wave --------
#define A0T_STR 72   // u16 units (144 B)
#define C1_STR 40    // u16 units (80 B)
__global__ __launch_bounds__(256) void k_conv(const float* __restrict__ x,
    const float* __restrict__ w0t, const float* __restrict__ b0,
    const u16* __restrict__ w1b, const float* __restrict__ b1,
    const float* __restrict__ w2t, const float* __restrict__ b2,
    float* __restrict__ h0){
  int w = threadIdx.x >> 6, lane = threadIdx.x & 63;
  int n = blockIdx.x*4 + w;
  __shared__ __align__(16) u16 a0t_s[4][36*A0T_STR];
  __shared__ float xs[4][160];
  __shared__ __align__(8) u16 a1s[4][64*4];
  u16* a0t = a0t_s[w];

  for (int i = lane; i < 160; i += 64) xs[w][i] = x[(size_t)n*160 + i];
  float w0r[7];
  #pragma unroll
  for (int k = 0; k < 7; k++) w0r[k] = w0t[k*64 + lane];
  float b0f = b0[lane];
  #pragma unroll
  for (int rp = 0; rp < 36; rp++)
    if (rp < 2 || rp >= 24) a0t[rp*A0T_STR + lane] = 0;

  #pragma unroll 1
  for (int q = 0; q < 22; q++){
    float win[13];
    #pragma unroll
    for (int j = 0; j < 13; j++) win[j] = xs[w][q*7 + j];
    float m = 0.f;
    #pragma unroll
    for (int r = 0; r < 7; r++){
      float s = b0f;
      #pragma unroll
      for (int k = 0; k < 7; k++) s += w0r[k]*win[r+k];
      m = fmaxf(m, s);
    }
    a0t[(2+q)*A0T_STR + lane] = f2bf(m);
  }

  int q = lane >> 4, r16 = lane & 15;
  float4v acc[4][2];
  #pragma unroll
  for (int mt = 0; mt < 4; mt++)
    #pragma unroll
    for (int nt = 0; nt < 2; nt++)
      acc[mt][nt] = (float4v){0.f,0.f,0.f,0.f};
  #pragma unroll 1
  for (int ks = 0; ks < 10; ks++){
    int kk = ks >> 1;
    int cbase = (ks & 1)*32 + q*8;
    bf16x8 af[4];
    #pragma unroll
    for (int mt = 0; mt < 4; mt++)
      af[mt] = *(const bf16x8*)(w1b + (16*mt + r16)*320 + ks*32 + q*8);
    bf16x8 bv[2];
    #pragma unroll
    for (int nt = 0; nt < 2; nt++)
      bv[nt] = *(const bf16x8*)(a0t + (r16 + 16*nt + kk)*A0T_STR + cbase);
    #pragma unroll
    for (int mt = 0; mt < 4; mt++)
      #pragma unroll
      for (int nt = 0; nt < 2; nt++)
        acc[mt][nt] = __builtin_amdgcn_mfma_f32_16x16x32_bf16(af[mt], bv[nt], acc[mt][nt], 0, 0, 0);
  }

  u16* c1 = a0t;
  #pragma unroll
  for (int mt = 0; mt < 4; mt++){
    float4 bb = *(const float4*)(b1 + 16*mt + 4*q);
    #pragma unroll
    for (int reg = 0; reg < 4; reg++){
      int m = 16*mt + q*4 + reg;
      float bv_ = ((const float*)&bb)[reg];
      c1[m*C1_STR + r16] = f2bf(fmaxf(acc[mt][0][reg] + bv_, 0.f));
      if (r16 <= 4)
        c1[m*C1_STR + 16 + r16] = f2bf(fmaxf(acc[mt][1][reg] + bv_, 0.f));
    }
  }

  {
    bf16x8 f0 = *(const bf16x8*)(c1 + lane*C1_STR);
    bf16x8 f1 = *(const bf16x8*)(c1 + lane*C1_STR + 8);
    bf16x8 f2 = *(const bf16x8*)(c1 + lane*C1_STR + 16);
    float v[24];
    #pragma unroll
    for (int j = 0; j < 8; j++){
      v[j]    = bf2f((u16)f0[j]);
      v[8+j]  = bf2f((u16)f1[j]);
      v[16+j] = bf2f((u16)f2[j]);
    }
    unsigned pk[2]; float mx[3];
    #pragma unroll
    for (int t = 0; t < 3; t++){
      float m = v[t*7];
      #pragma unroll
      for (int r = 1; r < 7; r++) m = fmaxf(m, v[t*7+r]);
      mx[t] = m;
    }
    pk[0] = (unsigned)f2bf(mx[0]) | ((unsigned)f2bf(mx[1]) << 16);
    pk[1] = (unsigned)f2bf(mx[2]);
    unsigned* a1d = (unsigned*)a1s[w];
    a1d[lane*2] = pk[0]; a1d[lane*2+1] = pk[1];
  }

  float s2 = b2[lane];
  const unsigned* a1d = (const unsigned*)a1s[w];
  #pragma unroll 1
  for (int c = 0; c < 64; c++){
    unsigned p0 = a1d[c*2], p1 = a1d[c*2+1];
    float t0 = bf2f(p0 & 0xffffu), t1 = bf2f(p0 >> 16), t2 = bf2f(p1 & 0xffffu);
    s2 += w2t[c*192 + lane]*t0 + w2t[c*192 + 64 + lane]*t1 + w2t[c*192 + 128 + lane]*t2;
  }
  h0[(size_t)n*64 + lane] = s2;
}

// ---------------- bn stats partials ----------------
__global__ __launch_bounds__(256) void k_stats1(const float* __restrict__ h0, float* __restrict__ stat1p){
  int b = blockIdx.x, tid = threadIdx.x;
  int col = tid & 63, rg = tid >> 6;
  float s = 0.f, s2 = 0.f;
  int r0 = b*244 + rg*61;
  #pragma unroll 1
  for (int t = 0; t < 61; t++){
    float v = h0[(size_t)(r0 + t)*64 + col];
    s += v; s2 += v*v;
  }
  __shared__ float ls[256], ls2[256];
  ls[tid] = s; ls2[tid] = s2;
  __syncthreads();
  if (tid < 64){
    stat1p[b*128 + tid]      = ls[tid] + ls[tid+64] + ls[tid+128] + ls[tid+192];
    stat1p[b*128 + 64 + tid] = ls2[tid] + ls2[tid+64] + ls2[tid+128] + ls2[tid+192];
  }
}

__global__ __launch_bounds__(256) void k_stats2(const u16* __restrict__ hB, float* __restrict__ stat2p){
  int b = blockIdx.x, tid = threadIdx.x;
  int col = tid & 127, rg = tid >> 7;
  float s = 0.f, s2 = 0.f;
  int r0 = b*244 + rg*122;
  #pragma unroll 1
  for (int t = 0; t < 122; t++){
    float v = bf2f(hB[(size_t)(r0 + t)*128 + col]);
    s += v; s2 += v*v;
  }
  __shared__ float ls[512];
  ls[tid] = s; ls[256 + tid] = s2;
  __syncthreads();
  if (tid < 128){
    stat2p[b*256 + tid]       = ls[tid] + ls[tid+128];
    stat2p[b*256 + 128 + tid] = ls[256+tid] + ls[256+tid+128];
  }
}

// ---------------- fused 3-layer GNN via MFMA, 8 waves per graph -------------
// All register arrays fully unrolled & preloaded (NO dynamic indexing -> no scratch).
#define HS_STR 136   // u16 (272 B)
#define HWT_STR 72   // u16 (144 B)
__global__ __launch_bounds__(512) void k_gnn(const float* __restrict__ h0,
    const float* __restrict__ stat1p,
    const float* __restrict__ bn1g, const float* __restrict__ bn1b,
    const u16* __restrict__ gwt0, const float* __restrict__ gb0,
    const u16* __restrict__ gwt1, const float* __restrict__ gb1,
    const u16* __restrict__ gwt2, const float* __restrict__ gb2,
    const u16* __restrict__ ewg_bf, u16* __restrict__ hB){
  int g = blockIdx.x, tid = threadIdx.x;
  int w = tid >> 6, lane = tid & 63, q = lane >> 4, r16 = lane & 15;
  int dt = w & 3, jh = w >> 2;          // phase2: d-tile, j-half
  __shared__ u16 hs[64*HS_STR];
  __shared__ u16 hwT[128*HWT_STR];
  __shared__ u16 ewl[64*EW_STR];
  __shared__ float bsc[64], bsh[64];

  // preload all weight fragments for this wave's j-tile (mt = w) — global loads
  bf16x8 af0[2], af1[4], af2[4];
  #pragma unroll
  for (int ks = 0; ks < 2; ks++)
    af0[ks] = *(const bf16x8*)(gwt0 + (16*w + r16)*64 + ks*32 + q*8);
  #pragma unroll
  for (int ks = 0; ks < 4; ks++)
    af1[ks] = *(const bf16x8*)(gwt1 + (16*w + r16)*128 + ks*32 + q*8);
  #pragma unroll
  for (int ks = 0; ks < 4; ks++)
    af2[ks] = *(const bf16x8*)(gwt2 + (16*w + r16)*128 + ks*32 + q*8);
  float4 b40 = *(const float4*)(gb0 + 16*w + 4*q);
  float4 b41 = *(const float4*)(gb1 + 16*w + 4*q);
  float4 b42 = *(const float4*)(gb2 + 16*w + 4*q);

  if (tid < 64){
    float s = 0.f, s2 = 0.f;
    #pragma unroll 1
    for (int r = 0; r < 32; r++){ s += stat1p[r*128 + tid]; s2 += stat1p[r*128 + 64 + tid]; }
    float m = s*(1.f/NNODES), v = s2*(1.f/NNODES) - m*m;
    float sc = rsqrtf(v + 1e-5f)*bn1g[tid];
    bsc[tid] = sc; bsh[tid] = bn1b[tid] - m*sc;
  }
  {
    const unsigned* src = (const unsigned*)ewg_bf + (size_t)g*(64*EW_STR/2);
    unsigned* dst = (unsigned*)ewl;
    for (int idx = tid; idx < 64*EW_STR/2; idx += 512) dst[idx] = src[idx];
  }
  {
    unsigned* hsd = (unsigned*)hs;
    for (int idx = tid; idx < 3*(HS_STR/2); idx += 512){
      int rr = 61 + idx/(HS_STR/2), cc = idx%(HS_STR/2);
      hsd[rr*(HS_STR/2) + cc] = 0;
    }
  }
  __syncthreads();   // bsc, ewl ready
  {
    unsigned* hsd = (unsigned*)hs;
    for (int idx = tid; idx < 61*32; idx += 512){
      int i = idx >> 5, kw = idx & 31;
      float2 hv = *(const float2*)(h0 + ((size_t)g*61 + i)*64 + kw*2);
      int k0 = kw*2;
      float a = hv.x*bsc[k0] + bsh[k0];
      float b = hv.y*bsc[k0+1] + bsh[k0+1];
      hsd[i*(HS_STR/2) + kw] = (unsigned)f2bf(a) | ((unsigned)f2bf(b) << 16);
    }
  }
  bf16x8 ewf[2];
  #pragma unroll
  for (int ks = 0; ks < 2; ks++)
    ewf[ks] = *(const bf16x8*)(ewl + (16*dt + r16)*EW_STR + ks*32 + q*8);
  __syncthreads();   // hs ready

  // ---------------- layer 0 (Cin=64, relu) ----------------
  #pragma unroll
  for (int nt = 0; nt < 4; nt++){
    float4v acc = {b40.x, b40.y, b40.z, b40.w};
    #pragma unroll
    for (int ks = 0; ks < 2; ks++){
      bf16x8 bv = *(const bf16x8*)(hs + (nt*16 + r16)*HS_STR + ks*32 + q*8);
      acc = __builtin_amdgcn_mfma_f32_16x16x32_bf16(af0[ks], bv, acc, 0, 0, 0);
    }
    #pragma unroll
    for (int r = 0; r < 4; r++)
      hwT[(16*w + 4*q + r)*HWT_STR + nt*16 + r16] = f2bf(acc[r]);
  }
  __syncthreads();
  #pragma unroll
  for (int nt = 0; nt < 4; nt++){
    int j = (jh*4 + nt)*16;
    float4v acc = {0.f,0.f,0.f,0.f};
    #pragma unroll
    for (int ks = 0; ks < 2; ks++){
      bf16x8 bv = *(const bf16x8*)(hwT + (j + r16)*HWT_STR + ks*32 + q*8);
      acc = __builtin_amdgcn_mfma_f32_16x16x32_bf16(ewf[ks], bv, acc, 0, 0, 0);
    }
    #pragma unroll
    for (int r = 0; r < 4; r++){
      int d = 16*dt + 4*q + r;
      hs[d*HS_STR + j + r16] = f2bf(fmaxf(acc[r], 0.f));
    }
  }
  __syncthreads();

  // ---------------- layer 1 (Cin=128, relu) ----------------
  #pragma unroll
  for (int nt = 0; nt < 4; nt++){
    float4v acc = {b41.x, b41.y, b41.z, b41.w};
    #pragma unroll
    for (int ks = 0; ks < 4; ks++){
      bf16x8 bv = *(const bf16x8*)(hs + (nt*16 + r16)*HS_STR + ks*32 + q*8);
      acc = __builtin_amdgcn_mfma_f32_16x16x32_bf16(af1[ks], bv, acc, 0, 0, 0);
    }
    #pragma unroll
    for (int r = 0; r < 4; r++)
      hwT[(16*w + 4*q + r)*HWT_STR + nt*16 + r16] = f2bf(acc[r]);
  }
  __syncthreads();
  #pragma unroll
  for (int nt = 0; nt < 4; nt++){
    int j = (jh*4 + nt)*16;
    float4v acc = {0.f,0.f,0.f,0.f};
    #pragma unroll
    for (int ks = 0; ks < 2; ks++){
      bf16x8 bv = *(const bf16x8*)(hwT + (j + r16)*HWT_STR + ks*32 + q*8);
      acc = __builtin_amdgcn_mfma_f32_16x16x32_bf16(ewf[ks], bv, acc, 0, 0, 0);
    }
    #pragma unroll
    for (int r = 0; r < 4; r++){
      int d = 16*dt + 4*q + r;
      hs[d*HS_STR + j + r16] = f2bf(fmaxf(acc[r], 0.f));
    }
  }
  __syncthreads();

  // ---------------- layer 2 (Cin=128, no relu, write hB) ----------------
  #pragma unroll
  for (int nt = 0; nt < 4; nt++){
    float4v acc = {b42.x, b42.y, b42.z, b42.w};
    #pragma unroll
    for (int ks = 0; ks < 4; ks++){
      bf16x8 bv = *(const bf16x8*)(hs + (nt*16 + r16)*HS_STR + ks*32 + q*8);
      acc = __builtin_amdgcn_mfma_f32_16x16x32_bf16(af2[ks], bv, acc, 0, 0, 0);
    }
    #pragma unroll
    for (int r = 0; r < 4; r++)
      hwT[(16*w + 4*q + r)*HWT_STR + nt*16 + r16] = f2bf(acc[r]);
  }
  __syncthreads();
  #pragma unroll
  for (int nt = 0; nt < 4; nt++){
    int j = (jh*4 + nt)*16;
    float4v acc = {0.f,0.f,0.f,0.f};
    #pragma unroll
    for (int ks = 0; ks < 2; ks++){
      bf16x8 bv = *(const bf16x8*)(hwT + (j + r16)*HWT_STR + ks*32 + q*8);
      acc = __builtin_amdgcn_mfma_f32_16x16x32_bf16(ewf[ks], bv, acc, 0, 0, 0);
    }
    #pragma unroll
    for (int r = 0; r < 4; r++){
      int d = 16*dt + 4*q + r;
      if (d < 61)
        hB[((size_t)g*61 + d)*128 + j + r16] = f2bf(acc[r]);
    }
  }
}

// ---------------- lin0 split-K via MFMA: block = (node pos i, o-half) -------
#define AS_STR 136
#define WT_STR 136
__global__ __launch_bounds__(256) void k_mlp0(const u16* __restrict__ hB,
    const float* __restrict__ stat2p,
    const float* __restrict__ bn2g, const float* __restrict__ bn2b,
    const float* __restrict__ lw0, float* __restrict__ part){
  int bi = blockIdx.x; int i = bi >> 1, oh = bi & 1;
  int tid = threadIdx.x, w = tid >> 6, lane = tid & 63, q = lane >> 4, r16 = lane & 15;
  __shared__ u16 As[128*AS_STR];
  __shared__ u16 wt[64*WT_STR];
  __shared__ float sc2[128], sh2[128];
  if (tid < 128){
    float s = 0.f, s2 = 0.f;
    #pragma unroll 1
    for (int r = 0; r < 32; r++){ s += stat2p[r*256 + tid]; s2 += stat2p[r*256 + 128 + tid]; }
    float m = s*(1.f/NNODES), v = s2*(1.f/NNODES) - m*m;
    float sc = rsqrtf(v + 1e-5f)*bn2g[tid];
    sc2[tid] = sc; sh2[tid] = bn2b[tid] - m*sc;
  }
  __syncthreads();
  {
    const unsigned* hbd = (const unsigned*)hB;
    unsigned* asd = (unsigned*)As;
    for (int idx = tid; idx < 8192; idx += 256){
      int gg = idx >> 6, kw = idx & 63;
      unsigned pv = hbd[((size_t)gg*61 + i)*64 + kw];
      int k0 = kw*2;
      float a = bf2f(pv & 0xffffu)*sc2[k0] + sh2[k0];
      float b = bf2f(pv >> 16)*sc2[k0+1] + sh2[k0+1];
      asd[gg*(AS_STR/2) + kw] = (unsigned)f2bf(a) | ((unsigned)f2bf(b) << 16);
    }
    for (int idx = tid; idx < 8192; idx += 256){
      int k = idx >> 6, o = idx & 63;
      wt[o*WT_STR + k] = f2bf(lw0[((size_t)i*128 + k)*128 + oh*64 + o]);
    }
  }
  __syncthreads();
  #pragma unroll 1
  for (int mi = 0; mi < 2; mi++){
    int mt = 2*w + mi;
    bf16x8 af[4];
    #pragma unroll
    for (int ks = 0; ks < 4; ks++)
      af[ks] = *(const bf16x8*)(As + (16*mt + r16)*AS_STR + ks*32 + q*8);
    #pragma unroll 1
    for (int nt = 0; nt < 4; nt++){
      float4v acc = {0.f,0.f,0.f,0.f};
      #pragma unroll
      for (int ks = 0; ks < 4; ks++){
        bf16x8 bv = *(const bf16x8*)(wt + (nt*16 + r16)*WT_STR + ks*32 + q*8);
        acc = __builtin_amdgcn_mfma_f32_16x16x32_bf16(af[ks], bv, acc, 0, 0, 0);
      }
      #pragma unroll
      for (int r = 0; r < 4; r++)
        part[(size_t)i*16384 + (size_t)(16*mt + 4*q + r)*128 + oh*64 + nt*16 + r16] = acc[r];
    }
  }
}

// ---------------- reduce partials + lin1 + lin2 + log_softmax ---------------
__global__ __launch_bounds__(256) void k_mlp1(const float* __restrict__ part,
    const float* __restrict__ lb0, const float* __restrict__ W1,
    const float* __restrict__ lb1, const float* __restrict__ W2,
    const float* __restrict__ lb2, float* __restrict__ out){
  int g = blockIdx.x, tid = threadIdx.x;
  int o = tid & 127, h = tid >> 7;
  __shared__ float y0[128], y1[128], red[256], y2[4];
  float acc = 0.f;
  int i0 = h*31, cnt = 31 - h;
  #pragma unroll 1
  for (int t = 0; t < cnt; t++)
    acc += part[(size_t)(i0 + t)*16384 + g*128 + o];
  red[tid] = acc;
  __syncthreads();
  if (tid < 128) y0[o] = fmaxf(red[o] + red[128 + o] + lb0[o], 0.f);
  __syncthreads();
  float a = 0.f;
  #pragma unroll 1
  for (int k = 0; k < 64; k++){
    int kk = h*64 + k;
    a += y0[kk]*W1[kk*128 + o];
  }
  red[tid] = a;
  __syncthreads();
  if (tid < 128) y1[o] = fmaxf(red[o] + red[128 + o] + lb1[o], 0.f);
  __syncthreads();
  if (tid < 4){
    float y = lb2[tid];
    #pragma unroll 1
    for (int k = 0; k < 128; k++) y += y1[k]*W2[k*4 + tid];
    y2[tid] = y;
  }
  __syncthreads();
  if (tid == 0){
    float m = fmaxf(fmaxf(y2[0],y2[1]), fmaxf(y2[2],y2[3]));
    float lse = m + logf(expf(y2[0]-m)+expf(y2[1]-m)+expf(y2[2]-m)+expf(y2[3]-m));
    out[g*4+0]=y2[0]-lse; out[g*4+1]=y2[1]-lse; out[g*4+2]=y2[2]-lse; out[g*4+3]=y2[3]-lse;
  }
}

extern "C" void kernel_launch(void* const* d_in, const int* in_sizes, int n_in,
                              void* d_out, int out_size, void* d_ws, size_t ws_size,
                              hipStream_t stream){
  const float* x    = (const float*)d_in[0];
  const float* ef   = (const float*)d_in[3];
  const float* cw0  = (const float*)d_in[4];
  const float* cb0  = (const float*)d_in[5];
  const float* cw1  = (const float*)d_in[6];
  const float* cb1  = (const float*)d_in[7];
  const float* cw2  = (const float*)d_in[8];
  const float* cb2  = (const float*)d_in[9];
  const float* bn1g = (const float*)d_in[10];
  const float* bn1b = (const float*)d_in[11];
  const float* gw0  = (const float*)d_in[12];
  const float* gb0  = (const float*)d_in[13];
  const float* gw1  = (const float*)d_in[14];
  const float* gb1  = (const float*)d_in[15];
  const float* gw2  = (const float*)d_in[16];
  const float* gb2  = (const float*)d_in[17];
  const float* bn2g = (const float*)d_in[18];
  const float* bn2b = (const float*)d_in[19];
  const float* lw0  = (const float*)d_in[20];
  const float* lb0  = (const float*)d_in[21];
  const float* lw1  = (const float*)d_in[22];
  const float* lb1  = (const float*)d_in[23];
  const float* lw2  = (const float*)d_in[24];
  const float* lb2  = (const float*)d_in[25];
  const float* eww  = (const float*)d_in[26];
  const float* ewb  = (const float*)d_in[27];
  float* out = (float*)d_out;

  float* ws   = (float*)d_ws;
  float* w1s  = ws;               // 10240 f (20480 u16)
  float* w2t  = w1s + 10240;      // 12288 f
  float* w0t  = w2t + 12288;      // 448 f
  float* gws0 = w0t + 448;        // 4096 f (8192 u16)
  float* gws1 = gws0 + 4096;      // 8192 f (16384 u16)
  float* gws2 = gws1 + 8192;      // 8192 f
  float* ew   = gws2 + 8192;      // 468480 f
  float* ewgs = ew + 468480;      // 294912 f (128*64*72 u16)
  float* h0   = ewgs + 294912;    // 499712 f
  float* hBs  = h0 + 499712;      // 499712 f (7808*128 u16)
  float* s1p  = hBs + 499712;     // 4096 f
  float* s2p  = s1p + 4096;       // 8192 f
  float* part = s2p + 8192;       // 999424 f

  u16* w1b    = (u16*)w1s;
  u16* gwt0   = (u16*)gws0;
  u16* gwt1   = (u16*)gws1;
  u16* gwt2   = (u16*)gws2;
  u16* ewg_bf = (u16*)ewgs;
  u16* hB     = (u16*)hBs;

  k_prep_w<<<290, 256, 0, stream>>>(cw0, cw1, cw2, gw0, gw1, gw2,
                                    w0t, w1b, w2t, gwt0, gwt1, gwt2);
  k_edge  <<<115, 256, 0, stream>>>(ef, eww, ewb, ew, out + 512);
  k_ewmat <<<NGRAPH, 256, 0, stream>>>(ew, ewg_bf);
  k_conv  <<<NNODES/4, 256, 0, stream>>>(x, w0t, cb0, w1b, cb1, w2t, cb2, h0);
  k_stats1<<<32, 256, 0, stream>>>(h0, s1p);
  k_gnn   <<<NGRAPH, 512, 0, stream>>>(h0, s1p, bn1g, bn1b,
                                       gwt0, gb0, gwt1, gb1, gwt2, gb2, ewg_bf, hB);
  k_stats2<<<32, 256, 0, stream>>>(hB, s2p);
  k_mlp0  <<<NPGN*2, 256, 0, stream>>>(hB, s2p, bn2g, bn2b, lw0, part);
  k_mlp1  <<<NGRAPH, 256, 0, stream>>>(part, lb0, lw1, lb1, lw2, lb2, out);
}

// Round 5
// 256.949 us; speedup vs baseline: 1.9781x; 1.2508x over previous
//
#include <hip/hip_runtime.h>
#include <math.h>

#define NPGN 61
#define NGRAPH 128
#define NNODES (NPGN*NGRAPH)   // 7808
#define EPG 3660               // 61*60 edges per graph

typedef float float4v __attribute__((ext_vector_type(4)));
typedef short bf16x8 __attribute__((ext_vector_type(8)));
typedef unsigned short u16;

__device__ __forceinline__ u16 f2bf(float v){
  union { float f; unsigned u; } x; x.f = v;
  unsigned r = (x.u + 0x7FFFu + ((x.u >> 16) & 1u)) >> 16;
  return (u16)r;
}
__device__ __forceinline__ float bf2f(unsigned u){
  union { unsigned u; float f; } x; x.u = u << 16;
  return x.f;
}

// ---------------- prep: weight re-layouts ----------------
// w1b[f*320+kk*64+c] bf16 ; w2b[f*192+k] bf16 (identity, cast) ; w0t[k*64+f] f32
// gwt_l[j*Cin+k] bf16 (K-minor)
__global__ __launch_bounds__(256) void k_prep_w(const float* __restrict__ w0,
    const float* __restrict__ w1, const float* __restrict__ w2,
    const float* __restrict__ gw0, const float* __restrict__ gw1, const float* __restrict__ gw2,
    float* __restrict__ w0t, u16* __restrict__ w1b, u16* __restrict__ w2b,
    u16* __restrict__ gwt0, u16* __restrict__ gwt1, u16* __restrict__ gwt2){
  int idx = blockIdx.x*256 + threadIdx.x;
  if (idx < 20480){
    int f = idx / 320, r = idx - f*320;
    int kk = r >> 6, c = r & 63;
    w1b[idx] = f2bf(w1[f*320 + c*5 + kk]);
  } else if (idx < 32768){
    int j = idx - 20480; w2b[j] = f2bf(w2[j]);
  } else if (idx < 40960){
    int j = idx - 32768; int jj = j >> 6, k = j & 63; gwt0[j] = f2bf(gw0[k*128 + jj]);
  } else if (idx < 57344){
    int j = idx - 40960; int jj = j >> 7, k = j & 127; gwt1[j] = f2bf(gw1[k*128 + jj]);
  } else if (idx < 73728){
    int j = idx - 57344; int jj = j >> 7, k = j & 127; gwt2[j] = f2bf(gw2[k*128 + jj]);
  } else if (idx < 74176){
    int j = idx - 73728; int k = j >> 6, f = j & 63; w0t[j] = w0[f*7 + k];
  }
}

// ---------------- edge weights ----------------
__global__ __launch_bounds__(256) void k_edge(const float* __restrict__ ef,
    const float* __restrict__ eww, const float* __restrict__ ewb,
    float* __restrict__ ew, float* __restrict__ out2){
  __shared__ float t[32][129];
  int i0 = blockIdx.x * 32;
  int tid = threadIdx.x;
  float w0 = eww[0], w1 = eww[1], w2 = eww[2], b = ewb[0];
  #pragma unroll 1
  for (int it = 0; it < 16; it++){
    int idx = it*256 + tid;
    int g = idx >> 5, ii = idx & 31;
    int i = i0 + ii;
    if (i < EPG){
      size_t e = (size_t)g*EPG + i;
      const float* p = ef + e*3;
      float v = tanhf(p[0]*w0 + p[1]*w1 + p[2]*w2 + b);
      ew[e] = v;
      t[ii][g] = v;
    }
  }
  __syncthreads();
  #pragma unroll 1
  for (int it = 0; it < 16; it++){
    int idx = it*256 + tid;
    int ii = idx >> 7, g = idx & 127;
    int i = i0 + ii;
    if (i < EPG) out2[(size_t)i*128 + g] = t[ii][g];
  }
}

// ---------------- dense per-graph edge matrix, bf16, [g][64][72] ------------
#define EW_STR 72
__global__ __launch_bounds__(256) void k_ewmat(const float* __restrict__ ew, u16* __restrict__ ewg_bf){
  int g = blockIdx.x, tid = threadIdx.x;
  __shared__ u16 t[64*EW_STR];
  unsigned* td = (unsigned*)t;
  for (int idx = tid; idx < 64*EW_STR/2; idx += 256) td[idx] = 0;
  __syncthreads();
  const float* e = ew + (size_t)g*EPG;
  for (int idx = tid; idx < EPG; idx += 256){
    int s = idx/60, r = idx - s*60;
    int d = r + (r >= s ? 1 : 0);
    t[d*EW_STR + s] = f2bf(e[idx]);
  }
  __syncthreads();
  unsigned* dst = (unsigned*)ewg_bf + (size_t)g*(64*EW_STR/2);
  for (int idx = tid; idx < 64*EW_STR/2; idx += 256) dst[idx] = td[idx];
}

// ---------------- conv stack: 4 independent waves/block, 1 node/wave --------
// conv0: scalar-load windows (wave-uniform x row) + VALU; conv1: MFMA; conv2: MFMA
#define A0T_STR 72   // u16 units (144 B)
#define C1_STR 40    // u16 units (80 B)
__global__ __launch_bounds__(256) void k_conv(const float* __restrict__ x,
    const float* __restrict__ w0t, const float* __restrict__ b0,
    const u16* __restrict__ w1b, const float* __restrict__ b1,
    const u16* __restrict__ w2b, const float* __restrict__ b2,
    float* __restrict__ h0){
  int w = threadIdx.x >> 6, lane = threadIdx.x & 63;
  int n = blockIdx.x*4 + w;
  __shared__ __align__(16) u16 a0t_s[4][36*A0T_STR];  // 5184 B/wave; c1 overlays
  __shared__ __align__(16) u16 a1k_s[4][208];         // conv2 input vector (192 + pad)
  u16* a0t = a0t_s[w];
  u16* a1k = a1k_s[w];

  // wave-uniform x row -> scalar loads
  const float* xrow = x + (size_t)__builtin_amdgcn_readfirstlane(n)*160;

  float w0r[7];
  #pragma unroll
  for (int k = 0; k < 7; k++) w0r[k] = w0t[k*64 + lane];
  float b0f = b0[lane];
  #pragma unroll
  for (int rp = 0; rp < 36; rp++)
    if (rp < 2 || rp >= 24) a0t[rp*A0T_STR + lane] = 0;

  // conv0 (K=7) + relu + maxpool7 : 160 -> 154 -> 22 ; lane = channel, pairs of outputs
  #pragma unroll 2
  for (int qp = 0; qp < 11; qp++){
    float win[20];
    #pragma unroll
    for (int j = 0; j < 20; j++) win[j] = xrow[14*qp + j];
    float m0, m1;
    #pragma unroll
    for (int r = 0; r < 7; r++){
      float s = w0r[0]*win[r];
      #pragma unroll
      for (int k = 1; k < 7; k++) s += w0r[k]*win[r+k];
      m0 = r ? fmaxf(m0, s) : s;
    }
    #pragma unroll
    for (int r = 7; r < 14; r++){
      float s = w0r[0]*win[r];
      #pragma unroll
      for (int k = 1; k < 7; k++) s += w0r[k]*win[r+k];
      m1 = (r > 7) ? fmaxf(m1, s) : s;
    }
    a0t[(2 + 2*qp)*A0T_STR + lane] = f2bf(fmaxf(m0 + b0f, 0.f));
    a0t[(3 + 2*qp)*A0T_STR + lane] = f2bf(fmaxf(m1 + b0f, 0.f));
  }

  // conv1 MFMA: C[64f][22p] = W[64f][320] * B[320][22p], k = kk*64 + c
  int q = lane >> 4, r16 = lane & 15;
  float4v acc[4][2];
  #pragma unroll
  for (int mt = 0; mt < 4; mt++)
    #pragma unroll
    for (int nt = 0; nt < 2; nt++)
      acc[mt][nt] = (float4v){0.f,0.f,0.f,0.f};
  #pragma unroll 1
  for (int ks = 0; ks < 10; ks++){
    int kk = ks >> 1;
    int cbase = (ks & 1)*32 + q*8;
    bf16x8 af[4];
    #pragma unroll
    for (int mt = 0; mt < 4; mt++)
      af[mt] = *(const bf16x8*)(w1b + (16*mt + r16)*320 + ks*32 + q*8);
    bf16x8 bv[2];
    #pragma unroll
    for (int nt = 0; nt < 2; nt++)
      bv[nt] = *(const bf16x8*)(a0t + (r16 + 16*nt + kk)*A0T_STR + cbase);
    #pragma unroll
    for (int mt = 0; mt < 4; mt++)
      #pragma unroll
      for (int nt = 0; nt < 2; nt++)
        acc[mt][nt] = __builtin_amdgcn_mfma_f32_16x16x32_bf16(af[mt], bv[nt], acc[mt][nt], 0, 0, 0);
  }

  // bias + relu -> c1 (bf16, overlays a0t; same-wave DS ops in-order)
  u16* c1 = a0t;
  #pragma unroll
  for (int mt = 0; mt < 4; mt++){
    float4 bb = *(const float4*)(b1 + 16*mt + 4*q);
    #pragma unroll
    for (int reg = 0; reg < 4; reg++){
      int m = 16*mt + q*4 + reg;
      float bv_ = ((const float*)&bb)[reg];
      c1[m*C1_STR + r16] = f2bf(fmaxf(acc[mt][0][reg] + bv_, 0.f));
      if (r16 <= 4)
        c1[m*C1_STR + 16 + r16] = f2bf(fmaxf(acc[mt][1][reg] + bv_, 0.f));
    }
  }

  // maxpool7 (21 -> 3), lane = channel; store contiguous k-vector a1k[c*3+t]
  {
    bf16x8 f0 = *(const bf16x8*)(c1 + lane*C1_STR);
    bf16x8 f1 = *(const bf16x8*)(c1 + lane*C1_STR + 8);
    bf16x8 f2 = *(const bf16x8*)(c1 + lane*C1_STR + 16);
    float v[24];
    #pragma unroll
    for (int j = 0; j < 8; j++){
      v[j]    = bf2f((u16)f0[j]);
      v[8+j]  = bf2f((u16)f1[j]);
      v[16+j] = bf2f((u16)f2[j]);
    }
    #pragma unroll
    for (int t = 0; t < 3; t++){
      float m = v[t*7];
      #pragma unroll
      for (int r = 1; r < 7; r++) m = fmaxf(m, v[t*7+r]);
      a1k[lane*3 + t] = f2bf(m);
    }
  }

  // conv2 via MFMA: C[f][*] = W2[64f][192k] * a1[192k], K = 6x32 exact
  float4v acc2[4];
  #pragma unroll
  for (int mt = 0; mt < 4; mt++) acc2[mt] = (float4v){0.f,0.f,0.f,0.f};
  #pragma unroll
  for (int ks = 0; ks < 6; ks++){
    bf16x8 bs = *(const bf16x8*)(a1k + ks*32 + q*8);   // broadcast; cols>0 garbage (ignored)
    #pragma unroll
    for (int mt = 0; mt < 4; mt++){
      bf16x8 af = *(const bf16x8*)(w2b + (16*mt + r16)*192 + ks*32 + q*8);
      acc2[mt] = __builtin_amdgcn_mfma_f32_16x16x32_bf16(af, bs, acc2[mt], 0, 0, 0);
    }
  }
  if (r16 == 0){
    #pragma unroll
    for (int mt = 0; mt < 4; mt++)
      #pragma unroll
      for (int reg = 0; reg < 4; reg++){
        int f = 16*mt + 4*q + reg;
        h0[(size_t)n*64 + f] = acc2[mt][reg] + b2[f];
      }
  }
}

// ---------------- bn stats partials, layout [col][32 blocks] ----------------
__global__ __launch_bounds__(256) void k_stats1(const float* __restrict__ h0, float* __restrict__ stat1p){
  int b = blockIdx.x, tid = threadIdx.x;
  int c4 = tid & 15, rg = tid >> 4;
  int r0 = b*244;
  float4v s = {0,0,0,0}, s2 = {0,0,0,0};
  #pragma unroll 1
  for (int t = 0; t < 15; t++){
    int r = r0 + rg + 16*t;
    float4v v = *(const float4v*)(h0 + (size_t)r*64 + c4*4);
    s += v; s2 += v*v;
  }
  if (rg < 4){
    int r = r0 + 240 + rg;
    float4v v = *(const float4v*)(h0 + (size_t)r*64 + c4*4);
    s += v; s2 += v*v;
  }
  __shared__ float red[16][128];
  #pragma unroll
  for (int cc = 0; cc < 4; cc++){
    red[rg][c4*4+cc] = s[cc];
    red[rg][64 + c4*4+cc] = s2[cc];
  }
  __syncthreads();
  if (tid < 128){
    float a = 0.f;
    #pragma unroll
    for (int r = 0; r < 16; r++) a += red[r][tid];
    if (tid < 64) stat1p[tid*32 + b] = a;
    else          stat1p[2048 + (tid-64)*32 + b] = a;
  }
}

__global__ __launch_bounds__(256) void k_stats2(const u16* __restrict__ hB, float* __restrict__ stat2p){
  int b = blockIdx.x, tid = threadIdx.x;
  int c4 = tid & 31, rg = tid >> 5;
  int r0 = b*244;
  float s[4] = {0,0,0,0}, s2[4] = {0,0,0,0};
  #pragma unroll 1
  for (int t = 0; t < 30; t++){
    int r = r0 + rg + 8*t;
    uint2 pv = *(const uint2*)(hB + (size_t)r*128 + c4*4);
    float v0 = bf2f(pv.x & 0xffffu), v1 = bf2f(pv.x >> 16);
    float v2 = bf2f(pv.y & 0xffffu), v3 = bf2f(pv.y >> 16);
    s[0]+=v0; s[1]+=v1; s[2]+=v2; s[3]+=v3;
    s2[0]+=v0*v0; s2[1]+=v1*v1; s2[2]+=v2*v2; s2[3]+=v3*v3;
  }
  if (rg < 4){
    int r = r0 + 240 + rg;
    uint2 pv = *(const uint2*)(hB + (size_t)r*128 + c4*4);
    float v0 = bf2f(pv.x & 0xffffu), v1 = bf2f(pv.x >> 16);
    float v2 = bf2f(pv.y & 0xffffu), v3 = bf2f(pv.y >> 16);
    s[0]+=v0; s[1]+=v1; s[2]+=v2; s[3]+=v3;
    s2[0]+=v0*v0; s2[1]+=v1*v1; s2[2]+=v2*v2; s2[3]+=v3*v3;
  }
  __shared__ float red[8][256];
  #pragma unroll
  for (int cc = 0; cc < 4; cc++){
    red[rg][c4*4+cc] = s[cc];
    red[rg][128 + c4*4+cc] = s2[cc];
  }
  __syncthreads();
  float a = 0.f;
  #pragma unroll
  for (int r = 0; r < 8; r++) a += red[r][tid];
  if (tid < 128) stat2p[tid*32 + b] = a;
  else           stat2p[4096 + (tid-128)*32 + b] = a;
}

// ---------------- fused 3-layer GNN via MFMA, 8 waves per graph -------------
#define HS_STR 136
#define HWT_STR 72
__global__ __launch_bounds__(512) void k_gnn(const float* __restrict__ h0,
    const float* __restrict__ stat1p,
    const float* __restrict__ bn1g, const float* __restrict__ bn1b,
    const u16* __restrict__ gwt0, const float* __restrict__ gb0,
    const u16* __restrict__ gwt1, const float* __restrict__ gb1,
    const u16* __restrict__ gwt2, const float* __restrict__ gb2,
    const u16* __restrict__ ewg_bf, u16* __restrict__ hB){
  int g = blockIdx.x, tid = threadIdx.x;
  int w = tid >> 6, lane = tid & 63, q = lane >> 4, r16 = lane & 15;
  int dt = w & 3, jh = w >> 2;
  __shared__ u16 hs[64*HS_STR];
  __shared__ u16 hwT[128*HWT_STR];
  __shared__ u16 ewl[64*EW_STR];
  __shared__ float bsc[64], bsh[64];

  bf16x8 af0[2], af1[4], af2[4];
  #pragma unroll
  for (int ks = 0; ks < 2; ks++)
    af0[ks] = *(const bf16x8*)(gwt0 + (16*w + r16)*64 + ks*32 + q*8);
  #pragma unroll
  for (int ks = 0; ks < 4; ks++)
    af1[ks] = *(const bf16x8*)(gwt1 + (16*w + r16)*128 + ks*32 + q*8);
  #pragma unroll
  for (int ks = 0; ks < 4; ks++)
    af2[ks] = *(const bf16x8*)(gwt2 + (16*w + r16)*128 + ks*32 + q*8);
  float4 b40 = *(const float4*)(gb0 + 16*w + 4*q);
  float4 b41 = *(const float4*)(gb1 + 16*w + 4*q);
  float4 b42 = *(const float4*)(gb2 + 16*w + 4*q);

  if (tid < 64){
    float4v sa = {0,0,0,0}, sb = {0,0,0,0};
    #pragma unroll
    for (int r = 0; r < 8; r++){
      sa += *(const float4v*)(stat1p + tid*32 + r*4);
      sb += *(const float4v*)(stat1p + 2048 + tid*32 + r*4);
    }
    float s = sa[0]+sa[1]+sa[2]+sa[3], s2 = sb[0]+sb[1]+sb[2]+sb[3];
    float m = s*(1.f/NNODES), v = s2*(1.f/NNODES) - m*m;
    float sc = rsqrtf(v + 1e-5f)*bn1g[tid];
    bsc[tid] = sc; bsh[tid] = bn1b[tid] - m*sc;
  }
  {
    const unsigned* src = (const unsigned*)ewg_bf + (size_t)g*(64*EW_STR/2);
    unsigned* dst = (unsigned*)ewl;
    for (int idx = tid; idx < 64*EW_STR/2; idx += 512) dst[idx] = src[idx];
  }
  {
    unsigned* hsd = (unsigned*)hs;
    for (int idx = tid; idx < 3*(HS_STR/2); idx += 512){
      int rr = 61 + idx/(HS_STR/2), cc = idx%(HS_STR/2);
      hsd[rr*(HS_STR/2) + cc] = 0;
    }
  }
  __syncthreads();
  {
    unsigned* hsd = (unsigned*)hs;
    for (int idx = tid; idx < 61*32; idx += 512){
      int i = idx >> 5, kw = idx & 31;
      float2 hv = *(const float2*)(h0 + ((size_t)g*61 + i)*64 + kw*2);
      int k0 = kw*2;
      float a = hv.x*bsc[k0] + bsh[k0];
      float b = hv.y*bsc[k0+1] + bsh[k0+1];
      hsd[i*(HS_STR/2) + kw] = (unsigned)f2bf(a) | ((unsigned)f2bf(b) << 16);
    }
  }
  bf16x8 ewf[2];
  #pragma unroll
  for (int ks = 0; ks < 2; ks++)
    ewf[ks] = *(const bf16x8*)(ewl + (16*dt + r16)*EW_STR + ks*32 + q*8);
  __syncthreads();

  // layer 0
  #pragma unroll
  for (int nt = 0; nt < 4; nt++){
    float4v acc = {b40.x, b40.y, b40.z, b40.w};
    #pragma unroll
    for (int ks = 0; ks < 2; ks++){
      bf16x8 bv = *(const bf16x8*)(hs + (nt*16 + r16)*HS_STR + ks*32 + q*8);
      acc = __builtin_amdgcn_mfma_f32_16x16x32_bf16(af0[ks], bv, acc, 0, 0, 0);
    }
    #pragma unroll
    for (int r = 0; r < 4; r++)
      hwT[(16*w + 4*q + r)*HWT_STR + nt*16 + r16] = f2bf(acc[r]);
  }
  __syncthreads();
  #pragma unroll
  for (int nt = 0; nt < 4; nt++){
    int j = (jh*4 + nt)*16;
    float4v acc = {0.f,0.f,0.f,0.f};
    #pragma unroll
    for (int ks = 0; ks < 2; ks++){
      bf16x8 bv = *(const bf16x8*)(hwT + (j + r16)*HWT_STR + ks*32 + q*8);
      acc = __builtin_amdgcn_mfma_f32_16x16x32_bf16(ewf[ks], bv, acc, 0, 0, 0);
    }
    #pragma unroll
    for (int r = 0; r < 4; r++){
      int d = 16*dt + 4*q + r;
      hs[d*HS_STR + j + r16] = f2bf(fmaxf(acc[r], 0.f));
    }
  }
  __syncthreads();

  // layer 1
  #pragma unroll
  for (int nt = 0; nt < 4; nt++){
    float4v acc = {b41.x, b41.y, b41.z, b41.w};
    #pragma unroll
    for (int ks = 0; ks < 4; ks++){
      bf16x8 bv = *(const bf16x8*)(hs + (nt*16 + r16)*HS_STR + ks*32 + q*8);
      acc = __builtin_amdgcn_mfma_f32_16x16x32_bf16(af1[ks], bv, acc, 0, 0, 0);
    }
    #pragma unroll
    for (int r = 0; r < 4; r++)
      hwT[(16*w + 4*q + r)*HWT_STR + nt*16 + r16] = f2bf(acc[r]);
  }
  __syncthreads();
  #pragma unroll
  for (int nt = 0; nt < 4; nt++){
    int j = (jh*4 + nt)*16;
    float4v acc = {0.f,0.f,0.f,0.f};
    #pragma unroll
    for (int ks = 0; ks < 2; ks++){
      bf16x8 bv = *(const bf16x8*)(hwT + (j + r16)*HWT_STR + ks*32 + q*8);
      acc = __builtin_amdgcn_mfma_f32_16x16x32_bf16(ewf[ks], bv, acc, 0, 0, 0);
    }
    #pragma unroll
    for (int r = 0; r < 4; r++){
      int d = 16*dt + 4*q + r;
      hs[d*HS_STR + j + r16] = f2bf(fmaxf(acc[r], 0.f));
    }
  }
  __syncthreads();

  // layer 2
  #pragma unroll
  for (int nt = 0; nt < 4; nt++){
    float4v acc = {b42.x, b42.y, b42.z, b42.w};
    #pragma unroll
    for (int ks = 0; ks < 4; ks++){
      bf16x8 bv = *(const bf16x8*)(hs + (nt*16 + r16)*HS_STR + ks*32 + q*8);
      acc = __builtin_amdgcn_mfma_f32_16x16x32_bf16(af2[ks], bv, acc, 0, 0, 0);
    }
    #pragma unroll
    for (int r = 0; r < 4; r++)
      hwT[(16*w + 4*q + r)*HWT_STR + nt*16 + r16] = f2bf(acc[r]);
  }
  __syncthreads();
  #pragma unroll
  for (int nt = 0; nt < 4; nt++){
    int j = (jh*4 + nt)*16;
    float4v acc = {0.f,0.f,0.f,0.f};
    #pragma unroll
    for (int ks = 0; ks < 2; ks++){
      bf16x8 bv = *(const bf16x8*)(hwT + (j + r16)*HWT_STR + ks*32 + q*8);
      acc = __builtin_amdgcn_mfma_f32_16x16x32_bf16(ewf[ks], bv, acc, 0, 0, 0);
    }
    #pragma unroll
    for (int r = 0; r < 4; r++){
      int d = 16*dt + 4*q + r;
      if (d < 61)
        hB[((size_t)g*61 + d)*128 + j + r16] = f2bf(acc[r]);
    }
  }
}

// ---------------- lin0 split-K via MFMA: block = (node pos i, o-half) -------
#define AS_STR 136
#define WT_STR 136
__global__ __launch_bounds__(256) void k_mlp0(const u16* __restrict__ hB,
    const float* __restrict__ stat2p,
    const float* __restrict__ bn2g, const float* __restrict__ bn2b,
    const float* __restrict__ lw0, float* __restrict__ part){
  int bi = blockIdx.x; int i = bi >> 1, oh = bi & 1;
  int tid = threadIdx.x, w = tid >> 6, lane = tid & 63, q = lane >> 4, r16 = lane & 15;
  __shared__ u16 As[128*AS_STR];
  __shared__ u16 wt[64*WT_STR];
  __shared__ float sc2[128], sh2[128];
  if (tid < 128){
    float4v sa = {0,0,0,0}, sb = {0,0,0,0};
    #pragma unroll
    for (int r = 0; r < 8; r++){
      sa += *(const float4v*)(stat2p + tid*32 + r*4);
      sb += *(const float4v*)(stat2p + 4096 + tid*32 + r*4);
    }
    float s = sa[0]+sa[1]+sa[2]+sa[3], s2 = sb[0]+sb[1]+sb[2]+sb[3];
    float m = s*(1.f/NNODES), v = s2*(1.f/NNODES) - m*m;
    float sc = rsqrtf(v + 1e-5f)*bn2g[tid];
    sc2[tid] = sc; sh2[tid] = bn2b[tid] - m*sc;
  }
  __syncthreads();
  {
    const unsigned* hbd = (const unsigned*)hB;
    unsigned* asd = (unsigned*)As;
    for (int idx = tid; idx < 8192; idx += 256){
      int gg = idx >> 6, kw = idx & 63;
      unsigned pv = hbd[((size_t)gg*61 + i)*64 + kw];
      int k0 = kw*2;
      float a = bf2f(pv & 0xffffu)*sc2[k0] + sh2[k0];
      float b = bf2f(pv >> 16)*sc2[k0+1] + sh2[k0+1];
      asd[gg*(AS_STR/2) + kw] = (unsigned)f2bf(a) | ((unsigned)f2bf(b) << 16);
    }
    for (int idx = tid; idx < 8192; idx += 256){
      int k = idx >> 6, o = idx & 63;
      wt[o*WT_STR + k] = f2bf(lw0[((size_t)i*128 + k)*128 + oh*64 + o]);
    }
  }
  __syncthreads();
  #pragma unroll 1
  for (int mi = 0; mi < 2; mi++){
    int mt = 2*w + mi;
    bf16x8 af[4];
    #pragma unroll
    for (int ks = 0; ks < 4; ks++)
      af[ks] = *(const bf16x8*)(As + (16*mt + r16)*AS_STR + ks*32 + q*8);
    #pragma unroll 1
    for (int nt = 0; nt < 4; nt++){
      float4v acc = {0.f,0.f,0.f,0.f};
      #pragma unroll
      for (int ks = 0; ks < 4; ks++){
        bf16x8 bv = *(const bf16x8*)(wt + (nt*16 + r16)*WT_STR + ks*32 + q*8);
        acc = __builtin_amdgcn_mfma_f32_16x16x32_bf16(af[ks], bv, acc, 0, 0, 0);
      }
      #pragma unroll
      for (int r = 0; r < 4; r++)
        part[(size_t)i*16384 + (size_t)(16*mt + 4*q + r)*128 + oh*64 + nt*16 + r16] = acc[r];
    }
  }
}

// ---------------- reduce partials + lin1 + lin2 + log_softmax, 512 thr ------
__global__ __launch_bounds__(512) void k_mlp1(const float* __restrict__ part,
    const float* __restrict__ lb0, const float* __restrict__ W1,
    const float* __restrict__ lb1, const float* __restrict__ W2,
    const float* __restrict__ lb2, float* __restrict__ out){
  int g = blockIdx.x, tid = threadIdx.x;
  int o = tid & 127, h = tid >> 7;   // h in 0..3
  __shared__ float red[512];
  __shared__ float y0[128], y1[128];
  float acc = 0.f;
  int i0 = h*16, cnt = (h == 3) ? 13 : 16;
  #pragma unroll 1
  for (int t = 0; t < cnt; t++)
    acc += part[(size_t)(i0 + t)*16384 + g*128 + o];
  red[tid] = acc;
  __syncthreads();
  if (tid < 128)
    y0[tid] = fmaxf(red[tid] + red[128+tid] + red[256+tid] + red[384+tid] + lb0[tid], 0.f);
  __syncthreads();
  float a = 0.f;
  #pragma unroll 1
  for (int t = 0; t < 32; t++){
    int k = h*32 + t;
    a += y0[k]*W1[k*128 + o];
  }
  red[tid] = a;
  __syncthreads();
  if (tid < 128)
    y1[tid] = fmaxf(red[tid] + red[128+tid] + red[256+tid] + red[384+tid] + lb1[tid], 0.f);
  __syncthreads();
  int k2 = tid >> 2, c2 = tid & 3;
  red[tid] = y1[k2]*W2[k2*4 + c2];
  __syncthreads();
  #pragma unroll
  for (int off = 256; off >= 4; off >>= 1){
    if (tid < off) red[tid] += red[tid + off];
    __syncthreads();
  }
  if (tid == 0){
    float v0 = red[0]+lb2[0], v1 = red[1]+lb2[1], v2 = red[2]+lb2[2], v3 = red[3]+lb2[3];
    float m = fmaxf(fmaxf(v0,v1), fmaxf(v2,v3));
    float lse = m + logf(expf(v0-m)+expf(v1-m)+expf(v2-m)+expf(v3-m));
    out[g*4+0]=v0-lse; out[g*4+1]=v1-lse; out[g*4+2]=v2-lse; out[g*4+3]=v3-lse;
  }
}

extern "C" void kernel_launch(void* const* d_in, const int* in_sizes, int n_in,
                              void* d_out, int out_size, void* d_ws, size_t ws_size,
                              hipStream_t stream){
  const float* x    = (const float*)d_in[0];
  const float* ef   = (const float*)d_in[3];
  const float* cw0  = (const float*)d_in[4];
  const float* cb0  = (const float*)d_in[5];
  const float* cw1  = (const float*)d_in[6];
  const float* cb1  = (const float*)d_in[7];
  const float* cw2  = (const float*)d_in[8];
  const float* cb2  = (const float*)d_in[9];
  const float* bn1g = (const float*)d_in[10];
  const float* bn1b = (const float*)d_in[11];
  const float* gw0  = (const float*)d_in[12];
  const float* gb0  = (const float*)d_in[13];
  const float* gw1  = (const float*)d_in[14];
  const float* gb1  = (const float*)d_in[15];
  const float* gw2  = (const float*)d_in[16];
  const float* gb2  = (const float*)d_in[17];
  const float* bn2g = (const float*)d_in[18];
  const float* bn2b = (const float*)d_in[19];
  const float* lw0  = (const float*)d_in[20];
  const float* lb0  = (const float*)d_in[21];
  const float* lw1  = (const float*)d_in[22];
  const float* lb1  = (const float*)d_in[23];
  const float* lw2  = (const float*)d_in[24];
  const float* lb2  = (const float*)d_in[25];
  const float* eww  = (const float*)d_in[26];
  const float* ewb  = (const float*)d_in[27];
  float* out = (float*)d_out;

  float* ws   = (float*)d_ws;
  float* w1s  = ws;               // 10240 f (20480 u16)
  float* w2s  = w1s + 10240;      // 6144 f (12288 u16)
  float* w0t  = w2s + 6144;       // 448 f
  float* gws0 = w0t + 448;        // 4096 f
  float* gws1 = gws0 + 4096;      // 8192 f
  float* gws2 = gws1 + 8192;      // 8192 f
  float* ew   = gws2 + 8192;      // 468480 f
  float* ewgs = ew + 468480;      // 294912 f
  float* h0   = ewgs + 294912;    // 499712 f
  float* hBs  = h0 + 499712;      // 499712 f
  float* s1p  = hBs + 499712;     // 4096 f
  float* s2p  = s1p + 4096;       // 8192 f
  float* part = s2p + 8192;       // 999424 f

  u16* w1b    = (u16*)w1s;
  u16* w2b    = (u16*)w2s;
  u16* gwt0   = (u16*)gws0;
  u16* gwt1   = (u16*)gws1;
  u16* gwt2   = (u16*)gws2;
  u16* ewg_bf = (u16*)ewgs;
  u16* hB     = (u16*)hBs;

  k_prep_w<<<290, 256, 0, stream>>>(cw0, cw1, cw2, gw0, gw1, gw2,
                                    w0t, w1b, w2b, gwt0, gwt1, gwt2);
  k_edge  <<<115, 256, 0, stream>>>(ef, eww, ewb, ew, out + 512);
  k_ewmat <<<NGRAPH, 256, 0, stream>>>(ew, ewg_bf);
  k_conv  <<<NNODES/4, 256, 0, stream>>>(x, w0t, cb0, w1b, cb1, w2b, cb2, h0);
  k_stats1<<<32, 256, 0, stream>>>(h0, s1p);
  k_gnn   <<<NGRAPH, 512, 0, stream>>>(h0, s1p, bn1g, bn1b,
                                       gwt0, gb0, gwt1, gb1, gwt2, gb2, ewg_bf, hB);
  k_stats2<<<32, 256, 0, stream>>>(hB, s2p);
  k_mlp0  <<<NPGN*2, 256, 0, stream>>>(hB, s2p, bn2g, bn2b, lw0, part);
  k_mlp1  <<<NGRAPH, 512, 0, stream>>>(part, lb0, lw1, lb1, lw2, lb2, out);
}